// Round 15
// baseline (33.934 us; speedup 1.0000x reference)
//
#include <hip/hip_runtime.h>
#include <hip/hip_bf16.h>
#include <hip/hip_fp8.h>

// VQ-VAE quantize: x[32,64,64,64] NCHW fp32, codebook[512,64] fp32.
// out[0] = 1.25*SSD/8388608 ; out[1..] = codebook[argmin] in NCHW.
// R15 = R14 (fp8 scan, 33.3us) with phase-B split into a store kernel whose
// blocks own CONTIGUOUS OUTPUT (image, 4 d-planes): idx[4096] + cbT-slice in
// LDS, gathers are LDS reads, stores are perfectly linear float4 streams.
// Hypothesis: R14's scattered 256B-chunk NCHW stores (~1-1.5 TB/s effective)
// were the dominant cost; linear stores should run at ~6 TB/s.
// k1 = R14 scan minus phase B (idx -> ws as ushort, loss partial -> ws).
// Loss finalize folded into k2 block 0. 3 launches. ws = 313 KB.

typedef __attribute__((ext_vector_type(4))) float f32x4;

// ---- d_ws layout (bytes) ----
#define WS_CBF   0        // 32768: fp8 codebook B-fragments (32 ct x 2 kk x 512B)
#define WS_HN2   32768    // 2048:  (256 - 128*||c||^2) f32[512]
#define WS_RED   34816    // 16384: per-wave loss partials f32[4096]
#define WS_IDX   51200    // 262144: ushort idx[32][4096]
// total 313344 B

__device__ __forceinline__ unsigned f2b1(float f) {
  unsigned u = __float_as_uint(f);
  return (u + 0x7FFFu + ((u >> 16) & 1)) >> 16;
}
__device__ __forceinline__ unsigned pack2(float lo, float hi) {
  return f2b1(lo) | (f2b1(hi) << 16);
}

#if defined(__has_builtin)
#  if __has_builtin(__builtin_amdgcn_cvt_pk_fp8_f32)
#    define HAVE_CVT_PK_FP8 1
#  endif
#endif
__device__ __forceinline__ unsigned cvt4_fp8(float a, float b, float c, float d) {
#ifdef HAVE_CVT_PK_FP8
  int v = __builtin_amdgcn_cvt_pk_fp8_f32(a, b, 0, false);
  v = __builtin_amdgcn_cvt_pk_fp8_f32(c, d, v, true);
  return (unsigned)v;
#else
  __hip_fp8_e4m3 fa(a), fb(b), fc(c), fd(d);
  return (unsigned)fa.__x | ((unsigned)fb.__x << 8) |
         ((unsigned)fc.__x << 16) | ((unsigned)fd.__x << 24);
#endif
}

// ================= k0: codebook -> fp8 fragment layout + hn2' =================
__global__ void vq_prep(const float* __restrict__ cb, char* __restrict__ ws) {
  const int n = blockIdx.x * 64 + threadIdx.x;    // code 0..511
  const float4* cb4 = (const float4*)cb;
  float4 f[16];
  #pragma unroll
  for (int j = 0; j < 16; ++j) f[j] = cb4[(n << 4) + j];
  float s = 0.f;
  #pragma unroll
  for (int j = 0; j < 16; ++j)
    s += f[j].x * f[j].x + f[j].y * f[j].y + f[j].z * f[j].z + f[j].w * f[j].w;
  ((float*)(ws + WS_HN2))[n] = 256.0f - 128.0f * s;   // 256*(1 - c^2/2)
  const int ct = n >> 4, col = n & 15;
  // B-fragment: lane = (g<<4)|col holds code ct*16+col, k = kk*32+g*8+e (8 fp8)
  #pragma unroll
  for (int kk = 0; kk < 2; ++kk) {
    #pragma unroll
    for (int g = 0; g < 4; ++g) {
      float4 a = f[kk * 8 + g * 2], b = f[kk * 8 + g * 2 + 1];
      uint2 u;
      u.x = cvt4_fp8(a.x * 256.f, a.y * 256.f, a.z * 256.f, a.w * 256.f);
      u.y = cvt4_fp8(b.x * 256.f, b.y * 256.f, b.z * 256.f, b.w * 256.f);
      *(uint2*)(ws + WS_CBF + (((ct << 1) + kk) << 9) + (((g << 4) | col) << 3)) = u;
    }
  }
}

// ================= k1: argmin + loss partials + idx -> ws =================
__global__ void __launch_bounds__(128, 4)
vq_argmin(const float* __restrict__ x, char* __restrict__ ws) {
  __shared__ __align__(16) char smem[6144];
  char*  xaz  = smem;                     // fp8 x-tile [64 rows][64B] swizzled
  float* hn2z = (float*)(smem + 4096);    // hn2' f32[512]

  const int t    = threadIdx.x;           // 0..127
  const int bid  = blockIdx.x;            // 0..2047
  const int bimg = bid >> 6;              // image 0..31
  const int hw0  = (bid & 63) << 6;       // 64-row hw tile
  const float4* xb4 = (const float4*)(x + (bimg << 18) + hw0);
  const long*   cbl = (const long*)(ws + WS_CBF);   // fragment-linear fp8

  // ---- stage X tile: fp8 [row][64B] swizzled; 8-lane groups read 128B ----
  float xsq = 0.f;
  {
    const int q = t >> 3;                 // d-quad 0..15 (planes 4q..4q+3)
    const int c = t & 7;                  // chunk
    #pragma unroll
    for (int j = 0; j < 2; ++j) {
      const int f = c + (j << 3);         // float4-row-group 0..15
      float4 A0 = xb4[((4 * q + 0) << 10) + f];
      float4 A1 = xb4[((4 * q + 1) << 10) + f];
      float4 A2 = xb4[((4 * q + 2) << 10) + f];
      float4 A3 = xb4[((4 * q + 3) << 10) + f];
      xsq += A0.x*A0.x + A0.y*A0.y + A0.z*A0.z + A0.w*A0.w;
      xsq += A1.x*A1.x + A1.y*A1.y + A1.z*A1.z + A1.w*A1.w;
      xsq += A2.x*A2.x + A2.y*A2.y + A2.z*A2.z + A2.w*A2.w;
      xsq += A3.x*A3.x + A3.y*A3.y + A3.z*A3.z + A3.w*A3.w;
      const float* a0 = (const float*)&A0;
      const float* a1 = (const float*)&A1;
      const float* a2 = (const float*)&A2;
      const float* a3 = (const float*)&A3;
      #pragma unroll
      for (int u = 0; u < 4; ++u) {
        int r = (f << 2) + u;
        unsigned pk = cvt4_fp8(a0[u], a1[u], a2[u], a3[u]);
        *(unsigned*)(xaz + r * 64 + ((q << 2) ^ ((r & 7) << 3))) = pk;
      }
    }
  }
  // ---- hn2' from prep ----
  #pragma unroll
  for (int i = 0; i < 4; ++i)
    hn2z[t + (i << 7)] = ((const float*)(ws + WS_HN2))[t + (i << 7)];
  __syncthreads();                        // the only barrier

  const int lane = t & 63;
  const int wid  = t >> 6;                // 0..1
  const int lrow = lane & 15;
  const int hb   = (lane >> 4) << 3;      // k-group byte offset

  // A fragments persist in regs (2 row-subtiles x 2 k-steps, 8B each)
  long af[2][2];
  #pragma unroll
  for (int s = 0; s < 2; ++s) {
    int row = (wid << 5) + (s << 4) + lrow;
    int sw = (row & 7) << 3;
    af[s][0] = *(const long*)(xaz + row * 64 + (hb ^ sw));
    af[s][1] = *(const long*)(xaz + row * 64 + ((32 | hb) ^ sw));
  }

  unsigned bestu[2][4];
  #pragma unroll
  for (int s = 0; s < 2; ++s)
    #pragma unroll
    for (int r = 0; r < 4; ++r) bestu[s][r] = 0u;   // score' > 0 always

  const unsigned tag0 = 511u - (unsigned)lrow;

  // ---- main loop: fp8 B direct from L1-resident ws ----
  #pragma unroll 2
  for (int ct = 0; ct < 32; ++ct) {
    const long b0 = cbl[(ct << 7) + lane];          // kk=0 fragment (8B)
    const long b1 = cbl[(ct << 7) + 64 + lane];     // kk=1 fragment
    const float hv = hn2z[(ct << 4) + lrow];        // 256 - 128*c^2
    const unsigned tag = tag0 - (unsigned)(ct << 4);  // 511 - nc
    #pragma unroll
    for (int s = 0; s < 2; ++s) {
      f32x4 acc = {hv, hv, hv, hv};
      acc = __builtin_amdgcn_mfma_f32_16x16x32_fp8_fp8(af[s][0], b0, acc, 0, 0, 0);
      acc = __builtin_amdgcn_mfma_f32_16x16x32_fp8_fp8(af[s][1], b1, acc, 0, 0, 0);
      #pragma unroll
      for (int r = 0; r < 4; ++r) {
        unsigned key = (__float_as_uint(acc[r]) & 0xFFFFFE00u) | tag;
        bestu[s][r] = max(bestu[s][r], key);
      }
    }
  }

  // ---- cross-lane key-max + idx (ushort -> ws) + loss partial ----
  unsigned short* wsid = (unsigned short*)(ws + WS_IDX);
  float vsum = 0.f;
  #pragma unroll
  for (int s = 0; s < 2; ++s) {
    #pragma unroll
    for (int r = 0; r < 4; ++r) {
      unsigned k = bestu[s][r];
      #pragma unroll
      for (int m = 1; m <= 8; m <<= 1) k = max(k, (unsigned)__shfl_xor(k, m, 64));
      if (lrow == 0) {
        const int row = (wid << 5) + (s << 4) + ((lane >> 4) << 2) + r;
        wsid[(bid << 6) + row] = (unsigned short)(511u - (k & 511u));
        vsum += fmaf(__uint_as_float(k & 0xFFFFFE00u), 1.0f / 256.0f, -1.0f);
      }
    }
  }
  float lacc = xsq - 2.0f * vsum;
  #pragma unroll
  for (int m = 32; m; m >>= 1) lacc += __shfl_xor(lacc, m, 64);
  if (lane == 0) ((float*)(ws + WS_RED))[(bid << 1) + wid] = lacc;
}

// ===== k2: contiguous-output scatter (image, 4 d-planes) + loss finalize =====
__global__ void __launch_bounds__(256, 2)
vq_scatter(const float* __restrict__ cb, const char* __restrict__ ws,
           float* __restrict__ out) {
  __shared__ __align__(16) unsigned short idxl[4096];  // 8 KB
  __shared__ __align__(16) float cbtl[4][512];         // 8 KB
  __shared__ float redl[4];
  const int t   = threadIdx.x;            // 0..255
  const int b   = blockIdx.x;             // 0..511
  const int img = b >> 4;                 // 0..31
  const int dbase = (b & 15) << 2;        // planes dbase..dbase+3

  // ---- stage idx[4096] of this image (vectorized) ----
  {
    const uint4* ig = (const uint4*)(ws + WS_IDX + (img << 13));
    ((uint4*)idxl)[t]       = ig[t];
    ((uint4*)idxl)[t + 256] = ig[t + 256];
  }
  // ---- stage d-major codebook slice: cbtl[j][code] = cb[code][dbase+j] ----
  {
    const int c0 = t << 1;
    float4 v0 = *(const float4*)(cb + (c0 << 6) + dbase);
    float4 v1 = *(const float4*)(cb + ((c0 + 1) << 6) + dbase);
    cbtl[0][c0] = v0.x; cbtl[1][c0] = v0.y;
    cbtl[2][c0] = v0.z; cbtl[3][c0] = v0.w;
    cbtl[0][c0 + 1] = v1.x; cbtl[1][c0 + 1] = v1.y;
    cbtl[2][c0 + 1] = v1.z; cbtl[3][c0 + 1] = v1.w;
  }
  // ---- block 0: loss finalize from k1 partials ----
  if (b == 0) {
    const float* red = (const float*)(ws + WS_RED);
    float v = 0.f;
    #pragma unroll
    for (int k = 0; k < 16; ++k) v += red[t + (k << 8)];
    #pragma unroll
    for (int m = 32; m; m >>= 1) v += __shfl_xor(v, m, 64);
    if ((t & 63) == 0) redl[t >> 6] = v;
  }
  __syncthreads();
  if (b == 0 && t == 0)
    out[0] = (redl[0] + redl[1] + redl[2] + redl[3]) * (1.25f / 8388608.0f);

  // ---- stream: 4 planes x 16 KB fully contiguous float4 stores ----
  float* ob = out + 1 + (img << 18) + (dbase << 12);
  #pragma unroll
  for (int j = 0; j < 4; ++j) {
    const float* cp = cbtl[j];
    float* op = ob + (j << 12);
    #pragma unroll
    for (int cc = 0; cc < 4; ++cc) {
      const int r0 = ((cc << 8) + t) << 2;           // rows r0..r0+3
      float4 v = {cp[idxl[r0 + 0]], cp[idxl[r0 + 1]],
                  cp[idxl[r0 + 2]], cp[idxl[r0 + 3]]};
      *(float4*)(op + r0) = v;                       // linear 16B, coalesced
    }
  }
}

extern "C" void kernel_launch(void* const* d_in, const int* in_sizes, int n_in,
                              void* d_out, int out_size, void* d_ws, size_t ws_size,
                              hipStream_t stream) {
  const float* x  = (const float*)d_in[0];   // 32*64*64*64 fp32 NCHW
  const float* cb = (const float*)d_in[1];   // 512*64 fp32
  float* out = (float*)d_out;                // [0]=loss, [1..]=quantized NCHW
  char*  ws  = (char*)d_ws;                  // 313 KB used
  vq_prep<<<8, 64, 0, stream>>>(cb, ws);
  vq_argmin<<<2048, 128, 0, stream>>>(x, ws);
  vq_scatter<<<512, 256, 0, stream>>>(cb, ws, out);
}